// Round 8
// baseline (781.351 us; speedup 1.0000x reference)
//
#include <hip/hip_runtime.h>

// ---------------- problem constants ----------------
#define NB      8
#define SEQ     4096
#define DM      512
#define DFF     2048
#define NE      8
#define NTOK    32768            // NB*SEQ
#define NPB     2097152          // SEQ*DM elems per batch
#define MAXROWS 67584            // 264 * 256 >= 65536 + 8*255
#define MAXT256 264              // 256-row tiles

// output layout (fp32 elements)
#define OUT_LB   16777216
#define OUT_TOPK 16777217
#define OUT_TASK 16842753

// ws byte offsets
#define WS_BSTATS   0            // double[8][1024][2]
#define WS_DMEAN    131072
#define WS_DRSTD    131136
#define WS_DCOLSUM  131200
#define WS_DTASK    131264       // double[8][8]
#define WS_HIST     131776
#define WS_CURSOR   131808
#define WS_SEGOFF   131840
#define WS_HDR_END  131904
#define WS_ROUTE_E  131904       // int2[32768]
#define WS_ROUTE_P  394048       // float2[32768]
#define WS_ATOK     656192       // int[67584]
#define WS_APROB    926528       // float[67584]
#define WS_TOKPOS   1196864      // int[32768*2]
#define WS_W1T      1459008      // ushort[8*2048*512]
#define WS_W2T      18236224     // ushort[8*512*2048]
#define WS_XB       35013440     // ushort[32768*512]
#define WS_Y        68567872     // ushort[67584*512]
#define WS_H        137773888    // ushort[TPC*256*2048]

typedef __attribute__((ext_vector_type(4))) float  f32x4;
typedef __attribute__((ext_vector_type(8))) __bf16 bf16x8;
typedef __attribute__((ext_vector_type(8))) short  s16x8;

__device__ __forceinline__ unsigned short f2bf(float f) {
    unsigned int u = __builtin_bit_cast(unsigned int, f);
    u += 0x7FFFu + ((u >> 16) & 1u);
    return (unsigned short)(u >> 16);
}
__device__ __forceinline__ float bf2f(unsigned short b) {
    unsigned int u = ((unsigned int)b) << 16;
    return __builtin_bit_cast(float, u);
}
__device__ __forceinline__ unsigned int pkbf(float a, float b) {
    unsigned int r;
    asm("v_cvt_pk_bf16_f32 %0, %1, %2" : "=v"(r) : "v"(a), "v"(b));
    return r;
}

#define GLDS16(g, l)                                                              \
    __builtin_amdgcn_global_load_lds(                                             \
        (const __attribute__((address_space(1))) unsigned int*)(const void*)(g),  \
        (__attribute__((address_space(3))) unsigned int*)(void*)(l), 16, 0, 0)

// ---------------- weight transpose + bf16 convert ----------------
__global__ void k_transpose_bf16(const float* __restrict__ in,
                                 unsigned short* __restrict__ outT,
                                 int R, int C) {
    __shared__ float tile[32][33];
    int e = blockIdx.z;
    const float* src = in + (size_t)e * R * C;
    unsigned short* dst = outT + (size_t)e * R * C;
    int tx = threadIdx.x & 31, ty = threadIdx.x >> 5;
    int c0 = blockIdx.x * 32, r0 = blockIdx.y * 32;
#pragma unroll
    for (int i = 0; i < 4; i++) {
        int r = r0 + ty + i * 8;
        tile[ty + i * 8][tx] = src[(size_t)r * C + c0 + tx];
    }
    __syncthreads();
#pragma unroll
    for (int i = 0; i < 4; i++) {
        int rr = c0 + ty + i * 8;
        dst[(size_t)rr * R + r0 + tx] = f2bf(tile[tx][ty + i * 8]);
    }
}

// ---------------- fused: x -> bf16 copy + fp64 batch stats ----------------
__global__ void __launch_bounds__(256) k_xstats(const float* __restrict__ x,
                                                unsigned short* __restrict__ xb,
                                                double* __restrict__ bstats) {
    int b = blockIdx.y, cblk = blockIdx.x, t = threadIdx.x;
    size_t base = (size_t)b * NPB + (size_t)cblk * 2048 + (size_t)t * 8;
    float4 a = *(const float4*)(x + base);
    float4 v = *(const float4*)(x + base + 4);
    s16x8 o = {(short)f2bf(a.x), (short)f2bf(a.y), (short)f2bf(a.z), (short)f2bf(a.w),
               (short)f2bf(v.x), (short)f2bf(v.y), (short)f2bf(v.z), (short)f2bf(v.w)};
    *(s16x8*)(xb + base) = o;
    double s  = (double)a.x + (double)a.y + (double)a.z + (double)a.w
              + (double)v.x + (double)v.y + (double)v.z + (double)v.w;
    double ss = (double)a.x * a.x + (double)a.y * a.y + (double)a.z * a.z + (double)a.w * a.w
              + (double)v.x * v.x + (double)v.y * v.y + (double)v.z * v.z + (double)v.w * v.w;
    for (int o2 = 32; o2; o2 >>= 1) { s += __shfl_down(s, o2); ss += __shfl_down(ss, o2); }
    __shared__ double as_[4], ass_[4];
    int w = t >> 6;
    if ((t & 63) == 0) { as_[w] = s; ass_[w] = ss; }
    __syncthreads();
    if (t == 0) {
        s  = as_[0] + as_[1] + as_[2] + as_[3];
        ss = ass_[0] + ass_[1] + ass_[2] + ass_[3];
        bstats[(b * 1024 + cblk) * 2]     = s;
        bstats[(b * 1024 + cblk) * 2 + 1] = ss;
    }
}

// ---------------- finalize mean/rstd, gate colsum, task terms ----------------
__global__ void k_finalize(const double* __restrict__ bstats,
                           double* __restrict__ dmean, double* __restrict__ drstd,
                           double* __restrict__ dcolsum, double* __restrict__ dtask,
                           const float* __restrict__ gw, const float* __restrict__ gb,
                           const float* __restrict__ temb, const int* __restrict__ task_id,
                           float* __restrict__ out_task) {
    int t = threadIdx.x;
    int b = t >> 5, l = t & 31;
    double s = 0.0, ss = 0.0;
    for (int i = l; i < 1024; i += 32) {
        s  += bstats[(b * 1024 + i) * 2];
        ss += bstats[(b * 1024 + i) * 2 + 1];
    }
    for (int o = 16; o; o >>= 1) { s += __shfl_down(s, o, 32); ss += __shfl_down(ss, o, 32); }
    if (l == 0) {
        double N = (double)NPB;
        double m = s / N;
        double var = ss / N - m * m;
        dmean[b] = m;
        drstd[b] = 1.0 / sqrt(var + 1e-5);
    }
    __shared__ double colp[32][8];
    {
        int e = t & 7, g = t >> 3;
        double a = 0.0;
        for (int r = g * 16; r < g * 16 + 16; r++) a += (double)gw[r * 8 + e];
        colp[g][e] = a;
    }
    __syncthreads();
    if (t < 8) {
        double a = 0.0;
        for (int g = 0; g < 32; g++) a += colp[g][t];
        dcolsum[t] = a;
    }
    if (t < 64) {
        int b2 = t >> 3, e = t & 7;
        int tid = task_id[b2];
        double a = (double)gb[e];
        for (int d = 0; d < 64; d++)
            a += (double)temb[tid * 64 + d] * (double)gw[(512 + d) * 8 + e];
        dtask[t] = a;
    }
    if (t < 8) out_task[t] = (float)task_id[t];
}

// ---------------- gate: one THREAD per token (fp64, broadcast LDS reads) ----------------
__global__ void __launch_bounds__(256) k_gate(const float* __restrict__ x,
                                              const float* __restrict__ gw,
                                              const double* __restrict__ dmean,
                                              const double* __restrict__ drstd,
                                              const double* __restrict__ dcolsum,
                                              const double* __restrict__ dtask,
                                              int* __restrict__ hist,
                                              int2* __restrict__ route_e,
                                              float2* __restrict__ route_p,
                                              float* __restrict__ out_topk) {
    __shared__ float gws[DM * 8];
    __shared__ int lh[8];
    int t = threadIdx.x;
    if (t < 8) lh[t] = 0;
#pragma unroll
    for (int i = 0; i < 16; i++) gws[i * 256 + t] = gw[i * 256 + t];
    __syncthreads();

    int token = blockIdx.x * 256 + t;
    int b = token >> 12;
    const float4* xp = (const float4*)(x + (size_t)token * DM);

    double acc[8] = {0, 0, 0, 0, 0, 0, 0, 0};
#pragma unroll 2
    for (int i = 0; i < 128; i++) {
        float4 v = xp[i];
        double dx = v.x, dy = v.y, dz = v.z, dw = v.w;
        const float* g = &gws[i * 32];
#pragma unroll
        for (int e = 0; e < 8; e++)
            acc[e] += dx * (double)g[e] + dy * (double)g[8 + e]
                    + dz * (double)g[16 + e] + dw * (double)g[24 + e];
    }

    double m = dmean[b], rs = drstd[b];
    double lg[8];
#pragma unroll
    for (int e = 0; e < 8; e++) lg[e] = rs * (acc[e] - m * dcolsum[e]) + dtask[b * 8 + e];
    int i0 = 0;
#pragma unroll
    for (int e = 1; e < 8; e++) if (lg[e] > lg[i0]) i0 = e;
    int i1 = (i0 == 0) ? 1 : 0;
#pragma unroll
    for (int e = 0; e < 8; e++) if (e != i0 && lg[e] > lg[i1]) i1 = e;
    double d = exp(lg[i1] - lg[i0]);
    double p0 = 1.0 / (1.0 + d);
    double p1 = d / (1.0 + d);
    out_topk[token * 2]     = (float)i0;
    out_topk[token * 2 + 1] = (float)i1;
    atomicAdd(&lh[i0], 1);
    atomicAdd(&lh[i1], 1);
    route_e[token] = make_int2(i0, i1);
    route_p[token] = make_float2((float)p0, (float)p1);
    __syncthreads();
    if (t < 8) atomicAdd(&hist[t], lh[t]);
}

// ---------------- segment offsets (256-padded) + lb_loss ----------------
__global__ void k_offsets_lb(const int* __restrict__ hist, int* __restrict__ seg_off,
                             float* __restrict__ out_lb) {
    if (threadIdx.x == 0) {
        int off = 0;
        double ssd = 0.0;
        for (int e = 0; e < 8; e++) {
            seg_off[e] = off;
            off += (hist[e] + 255) & ~255;
            double d = (double)hist[e] - 8192.0;
            ssd += d * d;
        }
        seg_off[8] = off;
        double stdv = sqrt(ssd / 7.0);
        double m = 8192.0 + 1e-6;
        double r = stdv / m;
        *out_lb = (float)(r * r);
    }
}

// ---------------- scatter: LDS-aggregated two-level + inverse map ----------------
__global__ void __launch_bounds__(256) k_scatter(const int2* __restrict__ route_e,
                                                 const float2* __restrict__ route_p,
                                                 const int* __restrict__ seg_off,
                                                 int* __restrict__ cursor,
                                                 int* __restrict__ atok,
                                                 float* __restrict__ aprob,
                                                 int* __restrict__ tokpos) {
    __shared__ int lcount[8];
    __shared__ int lbase[8];
    int t = threadIdx.x;
    if (t < 8) lcount[t] = 0;
    __syncthreads();
    int tok = blockIdx.x * 256 + t;
    int2 e = route_e[tok];
    float2 p = route_p[tok];
    int p0 = atomicAdd(&lcount[e.x], 1);
    int p1 = atomicAdd(&lcount[e.y], 1);
    __syncthreads();
    if (t < 8) lbase[t] = atomicAdd(&cursor[t], lcount[t]);
    __syncthreads();
    int a0 = seg_off[e.x] + lbase[e.x] + p0;
    atok[a0] = tok; aprob[a0] = p.x;
    int a1 = seg_off[e.y] + lbase[e.y] + p1;
    atok[a1] = tok; aprob[a1] = p.y;
    tokpos[tok * 2]     = a0;
    tokpos[tok * 2 + 1] = a1;
}

// ============ 256x256-tile MFMA GEMMs: 8 waves, deep-prefetch counted-vmcnt ============
// LDS As/Bs[2][256][64] (128 KB). XOR swizzle: slot c holds source chunk c^(row&7).
// Schedule per K-tile kt: compute(buf=kt&1) -> barrier -> stage kt+2 -> vmcnt(8)
// (kt+1 landed, 8 loads stay in flight) -> barrier. Never drains in steady state.
// mfma(bfv, af): lane's 4 acc elems = 4 consecutive OUTPUT COLUMNS.

// ---------------- GEMM1: H[chunk] = silu(X_gather @ w1[e] + b1[e]) ----------------
__global__ void __launch_bounds__(512, 1) k_gemm1(const unsigned short* __restrict__ xb,
                                                  const unsigned short* __restrict__ w1t,
                                                  const float* __restrict__ b1,
                                                  const int* __restrict__ atok,
                                                  const int* __restrict__ seg_off,
                                                  unsigned short* __restrict__ H,
                                                  int t0) {
    int nwg = (int)gridDim.x;                       // TPC*8
    int bid = (int)blockIdx.x;
    int wg = (bid & 7) * (nwg >> 3) + (bid >> 3);
    int xt = wg >> 3, y = wg & 7;                   // NY = 8 (2048/256)
    int r0 = (t0 + xt) * 256;
    if (r0 >= seg_off[8]) return;
    int e = 0;
    while (seg_off[e + 1] <= r0) e++;
    int f0 = y * 256;

    int tid = threadIdx.x;
    int w = tid >> 6, l = tid & 63;
    int c = l & 7;

    __shared__ __align__(16) unsigned short As[2 * 256 * 64];
    __shared__ __align__(16) unsigned short Bs[2 * 256 * 64];

    const unsigned short* asrc[4];
    const unsigned short* bsrc[4];
    unsigned short*       adst[4];
    unsigned short*       bdst[4];
#pragma unroll
    for (int j = 0; j < 4; j++) {
        int row = j * 64 + w * 8 + (l >> 3);
        int cs = c ^ (row & 7);
        int tok = atok[r0 + row]; if (tok < 0) tok = 0;
        asrc[j] = xb + (size_t)tok * DM + cs * 8;
        bsrc[j] = w1t + ((size_t)e * DFF + f0 + row) * DM + cs * 8;
        adst[j] = &As[(j * 64 + w * 8) * 64];
        bdst[j] = &Bs[(j * 64 + w * 8) * 64];
    }

    f32x4 acc[8][4] = {};
    int wr = w >> 2, wc = w & 3, lr = l & 15, q = l >> 4;

    const int NK = DM / 64;                         // 8
    // prologue: stage kt0 -> buf0, kt1 -> buf1
#pragma unroll
    for (int j = 0; j < 4; j++) { GLDS16(asrc[j], adst[j]); GLDS16(bsrc[j], bdst[j]); }
#pragma unroll
    for (int j = 0; j < 4; j++) { GLDS16(asrc[j] + 64, adst[j] + 16384); GLDS16(bsrc[j] + 64, bdst[j] + 16384); }
    asm volatile("s_waitcnt vmcnt(8)" ::: "memory");
    __builtin_amdgcn_s_barrier();

    for (int kt = 0; kt < NK; ++kt) {
        const unsigned short* Ab = &As[(kt & 1) * 16384];
        const unsigned short* Bb = &Bs[(kt & 1) * 16384];
        __builtin_amdgcn_s_setprio(1);
#pragma unroll
        for (int ks = 0; ks < 2; ks++) {
            bf16x8 bfv[4];
#pragma unroll
            for (int n = 0; n < 4; n++) {
                int R = wc * 64 + n * 16 + lr;
                bfv[n] = *(const bf16x8*)&Bb[R * 64 + (((ks << 2) + q) ^ (R & 7)) * 8];
            }
#pragma unroll
            for (int m = 0; m < 8; m++) {
                int R = wr * 128 + m * 16 + lr;
                bf16x8 af = *(const bf16x8*)&Ab[R * 64 + (((ks << 2) + q) ^ (R & 7)) * 8];
#pragma unroll
                for (int n = 0; n < 4; n++)
                    acc[m][n] = __builtin_amdgcn_mfma_f32_16x16x32_bf16(bfv[n], af, acc[m][n], 0, 0, 0);
            }
        }
        __builtin_amdgcn_s_setprio(0);
        __builtin_amdgcn_sched_barrier(0);
        asm volatile("" ::: "memory");
        __builtin_amdgcn_s_barrier();               // all reads of buf done
        if (kt + 2 < NK) {
            int kn = (kt + 2) * 64;
            int off = (kt & 1) * 16384;
#pragma unroll
            for (int j = 0; j < 4; j++) {
                GLDS16(asrc[j] + kn, adst[j] + off);
                GLDS16(bsrc[j] + kn, bdst[j] + off);
            }
            asm volatile("s_waitcnt vmcnt(8)" ::: "memory");
        } else {
            asm volatile("s_waitcnt vmcnt(0)" ::: "memory");
        }
        __builtin_amdgcn_s_barrier();               // next buf ready
        __builtin_amdgcn_sched_barrier(0);
    }

    // epilogue: acc[m][n][j] -> H row (wr*128+m*16+lr), col f0 + wc*64+n*16+q*4+j
    const float* b1e = b1 + e * DFF + f0;
#pragma unroll
    for (int m = 0; m < 8; m++) {
        int r = wr * 128 + m * 16 + lr;
        unsigned short* hrow = H + ((size_t)xt * 256 + r) * DFF + f0;
#pragma unroll
        for (int n = 0; n < 4; n++) {
            int fc = wc * 64 + n * 16 + q * 4;
            float4 bias = *(const float4*)(b1e + fc);
            float v0 = acc[m][n][0] + bias.x; v0 = v0 / (1.0f + __expf(-v0));
            float v1 = acc[m][n][1] + bias.y; v1 = v1 / (1.0f + __expf(-v1));
            float v2 = acc[m][n][2] + bias.z; v2 = v2 / (1.0f + __expf(-v2));
            float v3 = acc[m][n][3] + bias.w; v3 = v3 / (1.0f + __expf(-v3));
            *(uint2*)(hrow + fc) = make_uint2(pkbf(v0, v1), pkbf(v2, v3));
        }
    }
}

// ---------------- GEMM2: Y[aidx] = H[chunk] @ w2[e]  (K=2048) ----------------
__global__ void __launch_bounds__(512, 1) k_gemm2(const unsigned short* __restrict__ H,
                                                  const unsigned short* __restrict__ w2t,
                                                  const int* __restrict__ seg_off,
                                                  unsigned short* __restrict__ Y,
                                                  int t0) {
    int nwg = (int)gridDim.x;                       // TPC*2, TPC%4==0
    int bid = (int)blockIdx.x;
    int wg = (bid & 7) * (nwg >> 3) + (bid >> 3);
    int xt = wg >> 1, y = wg & 1;                   // NY = 2 (512/256)
    int r0 = (t0 + xt) * 256;
    if (r0 >= seg_off[8]) return;
    int e = 0;
    while (seg_off[e + 1] <= r0) e++;
    int d0 = y * 256;

    int tid = threadIdx.x;
    int w = tid >> 6, l = tid & 63;
    int c = l & 7;

    __shared__ __align__(16) unsigned short As[2 * 256 * 64];
    __shared__ __align__(16) unsigned short Bs[2 * 256 * 64];

    const unsigned short* asrc[4];
    const unsigned short* bsrc[4];
    unsigned short*       adst[4];
    unsigned short*       bdst[4];
#pragma unroll
    for (int j = 0; j < 4; j++) {
        int row = j * 64 + w * 8 + (l >> 3);
        int cs = c ^ (row & 7);
        asrc[j] = H + ((size_t)xt * 256 + row) * DFF + cs * 8;
        bsrc[j] = w2t + ((size_t)e * DM + d0 + row) * DFF + cs * 8;
        adst[j] = &As[(j * 64 + w * 8) * 64];
        bdst[j] = &Bs[(j * 64 + w * 8) * 64];
    }

    f32x4 acc[8][4] = {};
    int wr = w >> 2, wc = w & 3, lr = l & 15, q = l >> 4;

    const int NK = DFF / 64;                        // 32
#pragma unroll
    for (int j = 0; j < 4; j++) { GLDS16(asrc[j], adst[j]); GLDS16(bsrc[j], bdst[j]); }
#pragma unroll
    for (int j = 0; j < 4; j++) { GLDS16(asrc[j] + 64, adst[j] + 16384); GLDS16(bsrc[j] + 64, bdst[j] + 16384); }
    asm volatile("s_waitcnt vmcnt(8)" ::: "memory");
    __builtin_amdgcn_s_barrier();

    for (int kt = 0; kt < NK; ++kt) {
        const unsigned short* Ab = &As[(kt & 1) * 16384];
        const unsigned short* Bb = &Bs[(kt & 1) * 16384];
        __builtin_amdgcn_s_setprio(1);
#pragma unroll
        for (int ks = 0; ks < 2; ks++) {
            bf16x8 bfv[4];
#pragma unroll
            for (int n = 0; n < 4; n++) {
                int R = wc * 64 + n * 16 + lr;
                bfv[n] = *(const bf16x8*)&Bb[R * 64 + (((ks << 2) + q) ^ (R & 7)) * 8];
            }
#pragma unroll
            for (int m = 0; m < 8; m++) {
                int R = wr * 128 + m * 16 + lr;
                bf16x8 af = *(const bf16x8*)&Ab[R * 64 + (((ks << 2) + q) ^ (R & 7)) * 8];
#pragma unroll
                for (int n = 0; n < 4; n++)
                    acc[m][n] = __builtin_amdgcn_mfma_f32_16x16x32_bf16(bfv[n], af, acc[m][n], 0, 0, 0);
            }
        }
        __builtin_amdgcn_s_setprio(0);
        __builtin_amdgcn_sched_barrier(0);
        asm volatile("" ::: "memory");
        __builtin_amdgcn_s_barrier();
        if (kt + 2 < NK) {
            int kn = (kt + 2) * 64;
            int off = (kt & 1) * 16384;
#pragma unroll
            for (int j = 0; j < 4; j++) {
                GLDS16(asrc[j] + kn, adst[j] + off);
                GLDS16(bsrc[j] + kn, bdst[j] + off);
            }
            asm volatile("s_waitcnt vmcnt(8)" ::: "memory");
        } else {
            asm volatile("s_waitcnt vmcnt(0)" ::: "memory");
        }
        __builtin_amdgcn_s_barrier();
        __builtin_amdgcn_sched_barrier(0);
    }

#pragma unroll
    for (int m = 0; m < 8; m++) {
        int r = wr * 128 + m * 16 + lr;
        unsigned short* yrow = Y + (size_t)(r0 + r) * DM + d0;
#pragma unroll
        for (int n = 0; n < 4; n++) {
            int dc = wc * 64 + n * 16 + q * 4;
            *(uint2*)(yrow + dc) = make_uint2(pkbf(acc[m][n][0], acc[m][n][1]),
                                              pkbf(acc[m][n][2], acc[m][n][3]));
        }
    }
}

// ---------------- combine: out[t] = p0*(Y[a0]+b2[e0]) + p1*(Y[a1]+b2[e1]) ----------------
__global__ void __launch_bounds__(256) k_combine(const unsigned short* __restrict__ Y,
                                                 const float* __restrict__ b2,
                                                 const int* __restrict__ tokpos,
                                                 const int2* __restrict__ route_e,
                                                 const float2* __restrict__ route_p,
                                                 float* __restrict__ out) {
    int gt = blockIdx.x * 256 + threadIdx.x;
    int token = gt >> 6;
    int cbase = (gt & 63) * 8;
    int2 e = route_e[token];
    float2 p = route_p[token];
    int a0 = tokpos[token * 2], a1 = tokpos[token * 2 + 1];
    s16x8 y0 = *(const s16x8*)(Y + (size_t)a0 * DM + cbase);
    s16x8 y1 = *(const s16x8*)(Y + (size_t)a1 * DM + cbase);
    const float4* bb0 = (const float4*)(b2 + e.x * DM + cbase);
    const float4* bb1 = (const float4*)(b2 + e.y * DM + cbase);
    float4 b00 = bb0[0], b01 = bb0[1];
    float4 b10 = bb1[0], b11 = bb1[1];
    float r[8];
    r[0] = p.x * (bf2f((unsigned short)y0[0]) + b00.x) + p.y * (bf2f((unsigned short)y1[0]) + b10.x);
    r[1] = p.x * (bf2f((unsigned short)y0[1]) + b00.y) + p.y * (bf2f((unsigned short)y1[1]) + b10.y);
    r[2] = p.x * (bf2f((unsigned short)y0[2]) + b00.z) + p.y * (bf2f((unsigned short)y1[2]) + b10.z);
    r[3] = p.x * (bf2f((unsigned short)y0[3]) + b00.w) + p.y * (bf2f((unsigned short)y1[3]) + b10.w);
    r[4] = p.x * (bf2f((unsigned short)y0[4]) + b01.x) + p.y * (bf2f((unsigned short)y1[4]) + b11.x);
    r[5] = p.x * (bf2f((unsigned short)y0[5]) + b01.y) + p.y * (bf2f((unsigned short)y1[5]) + b11.y);
    r[6] = p.x * (bf2f((unsigned short)y0[6]) + b01.z) + p.y * (bf2f((unsigned short)y1[6]) + b11.z);
    r[7] = p.x * (bf2f((unsigned short)y0[7]) + b01.w) + p.y * (bf2f((unsigned short)y1[7]) + b11.w);
    float* op = out + (size_t)token * DM + cbase;
    *(float4*)op       = make_float4(r[0], r[1], r[2], r[3]);
    *(float4*)(op + 4) = make_float4(r[4], r[5], r[6], r[7]);
}

// ---------------- launch ----------------
extern "C" void kernel_launch(void* const* d_in, const int* in_sizes, int n_in,
                              void* d_out, int out_size, void* d_ws, size_t ws_size,
                              hipStream_t stream) {
    const float* x       = (const float*)d_in[0];
    const int*   task_id = (const int*)d_in[1];
    const float* w1      = (const float*)d_in[2];
    const float* b1      = (const float*)d_in[3];
    const float* w2      = (const float*)d_in[4];
    const float* b2      = (const float*)d_in[5];
    const float* temb    = (const float*)d_in[6];
    const float* gw      = (const float*)d_in[7];
    const float* gb      = (const float*)d_in[8];
    float* out = (float*)d_out;

    char* ws = (char*)d_ws;
    double* bstats   = (double*)(ws + WS_BSTATS);
    double* dmean    = (double*)(ws + WS_DMEAN);
    double* drstd    = (double*)(ws + WS_DRSTD);
    double* dcolsum  = (double*)(ws + WS_DCOLSUM);
    double* dtask    = (double*)(ws + WS_DTASK);
    int*    hist     = (int*)(ws + WS_HIST);
    int*    cursor   = (int*)(ws + WS_CURSOR);
    int*    seg_off  = (int*)(ws + WS_SEGOFF);
    int2*   route_e  = (int2*)(ws + WS_ROUTE_E);
    float2* route_p  = (float2*)(ws + WS_ROUTE_P);
    int*    atok     = (int*)(ws + WS_ATOK);
    float*  aprob    = (float*)(ws + WS_APROB);
    int*    tokpos   = (int*)(ws + WS_TOKPOS);
    unsigned short* w1t = (unsigned short*)(ws + WS_W1T);
    unsigned short* w2t = (unsigned short*)(ws + WS_W2T);
    unsigned short* xb  = (unsigned short*)(ws + WS_XB);
    unsigned short* Y   = (unsigned short*)(ws + WS_Y);
    unsigned short* H   = (unsigned short*)(ws + WS_H);

    // tiles(256 rows) per chunk; multiple of 4 (grid%8 for both gemms); <=132 (2 chunks,
    // H chunk ~138 MB LLC-plausible)
    int TPC = (int)((ws_size - (size_t)WS_H) / (size_t)(256 * DFF * 2));
    if (TPC > 132) TPC = 132;
    TPC &= ~3;
    if (TPC < 4) TPC = 4;

    hipMemsetAsync(ws, 0, WS_HDR_END, stream);
    hipMemsetAsync(ws + WS_ATOK, 0xFF, (size_t)MAXROWS * sizeof(int), stream);

    k_transpose_bf16<<<dim3(DFF / 32, DM / 32, NE), 256, 0, stream>>>(w1, w1t, DM, DFF);
    k_transpose_bf16<<<dim3(DM / 32, DFF / 32, NE), 256, 0, stream>>>(w2, w2t, DFF, DM);

    // fused x->bf16 + stats
    k_xstats<<<dim3(1024, NB), 256, 0, stream>>>(x, xb, bstats);
    k_finalize<<<1, 256, 0, stream>>>(bstats, dmean, drstd, dcolsum, dtask,
                                      gw, gb, temb, task_id, out + OUT_TASK);

    k_gate<<<NTOK / 256, 256, 0, stream>>>(x, gw, dmean, drstd, dcolsum, dtask,
                                           hist, route_e, route_p, out + OUT_TOPK);
    k_offsets_lb<<<1, 64, 0, stream>>>(hist, seg_off, out + OUT_LB);
    k_scatter<<<NTOK / 256, 256, 0, stream>>>(route_e, route_p, seg_off, cursor,
                                              atok, aprob, tokpos);

    for (int t0 = 0; t0 < MAXT256; t0 += TPC) {
        k_gemm1<<<TPC * 8, 512, 0, stream>>>(xb, w1t, b1, atok, seg_off, H, t0);
        k_gemm2<<<TPC * 2, 512, 0, stream>>>(H, w2t, seg_off, Y, t0);
    }
    k_combine<<<NTOK / 4, 256, 0, stream>>>(Y, b2, tokpos, route_e, route_p, out);
}